// Round 1
// baseline (20744.073 us; speedup 1.0000x reference)
//
#include <hip/hip_runtime.h>
#include <math.h>

#define NB    4096
#define NH    128
#define NKIN  8
#define NKOUT 4
#define NTP   64
#define NL    128
#define BT    16      // batch rows per block
#define NTHR  512     // 8 waves
#define BKIN  (NB*NKIN)

__device__ __forceinline__ float fsig(float x)  { return 1.0f/(1.0f+__expf(-x)); }
__device__ __forceinline__ float ftanh(float x) { return 1.0f - 2.0f/(1.0f+__expf(2.0f*x)); }

// acc[g][i] += sum_k W[(g*128+hj)*128+k] * src[bbase+i][k]
__device__ __forceinline__ void gemv3_128(const float* __restrict__ W,
                                          const float (* __restrict__ src)[NH],
                                          int hj, int bbase, float acc[3][4])
{
    const float4* __restrict__ w0 = (const float4*)W + (hj)*32;
    const float4* __restrict__ w1 = (const float4*)W + (NH + hj)*32;
    const float4* __restrict__ w2 = (const float4*)W + (2*NH + hj)*32;
    #pragma unroll 4
    for (int k4 = 0; k4 < 32; ++k4) {
        float4 a0 = w0[k4], a1 = w1[k4], a2 = w2[k4];
        #pragma unroll
        for (int i = 0; i < 4; ++i) {
            float4 y = *(const float4*)&src[bbase + i][k4*4];
            acc[0][i] += a0.x*y.x + a0.y*y.y + a0.z*y.z + a0.w*y.w;
            acc[1][i] += a1.x*y.x + a1.y*y.y + a1.z*y.z + a1.w*y.w;
            acc[2][i] += a2.x*y.x + a2.y*y.y + a2.z*y.z + a2.w*y.w;
        }
    }
}

// ---------------- spline: tridiag(1,4,1) Thomas solve, one column per thread ----
__global__ void spline_kernel(const float* __restrict__ pre_x,
                              const float* __restrict__ fx,
                              float* __restrict__ M)
{
    __shared__ float cp[128];
    if (threadIdx.x == 0) {
        float cprev = 0.0f;
        for (int j = 1; j <= 127; ++j) { float ci = 1.0f/(4.0f - cprev); cp[j] = ci; cprev = ci; }
    }
    __syncthreads();
    int c = blockIdx.x * 256 + threadIdx.x;   // column = b*8 + k, 0..32767
    const float r6 = 6.0f/(0.1f*0.1f);
    float y0 = pre_x[(size_t)(NTP-1)*BKIN + c];  // ys[0] = pre_x[-1]
    float y1 = fx[c];                            // ys[1]
    float dprev = 0.0f;
    for (int j = 1; j <= 127; ++j) {
        float y2 = fx[(size_t)j*BKIN + c];       // ys[j+1]
        float r  = r6*(y0 - 2.0f*y1 + y2);
        float d  = (r - dprev)*cp[j];
        M[(size_t)j*BKIN + c] = d;
        dprev = d; y0 = y1; y1 = y2;
    }
    float xnext = 0.0f;
    for (int j = 127; j >= 1; --j) {
        float x = M[(size_t)j*BKIN + c] - cp[j]*xnext;
        M[(size_t)j*BKIN + c] = x;
        xnext = x;
    }
    M[c] = 0.0f;
    M[(size_t)128*BKIN + c] = 0.0f;
}

// ---------------- fused encoder + RK4 + head ----------------
__global__ void __launch_bounds__(NTHR, 2)
fused_kernel(const float* __restrict__ pre_x, const float* __restrict__ pre_y,
             const float* __restrict__ fx,
             const float* __restrict__ W_ih, const float* __restrict__ W_hh,
             const float* __restrict__ b_ih, const float* __restrict__ b_hh,
             const float* __restrict__ W_e,  const float* __restrict__ b_e,
             const float* __restrict__ Wc_ih,const float* __restrict__ Wc_hh,
             const float* __restrict__ bc_ih,const float* __restrict__ bc_hh,
             const float* __restrict__ W1,   const float* __restrict__ W2,
             const float* __restrict__ M,    float* __restrict__ out)
{
    __shared__ float sh_y [BT][NH];
    __shared__ float sh_ye[BT][NH];
    __shared__ float sh_x0[BT][NH];
    __shared__ float sh_xm[BT][NH];
    __shared__ float sh_x1[BT][NH];
    __shared__ float sh_u [3][BT][NKIN];
    __shared__ float sh_in[BT][12];
    __shared__ float sh_o [BT][2*NH + 4];   // pad 4 -> conflict-free + float4 aligned

    const int tid   = threadIdx.x;
    const int hj    = tid & (NH-1);
    const int bs    = tid >> 7;        // 0..3
    const int bbase = bs*4;
    const int b0    = blockIdx.x * BT;

    // per-thread constants
    const float bir_e = b_ih[hj], biz_e = b_ih[NH+hj], bin_e = b_ih[2*NH+hj];
    const float bhr_e = b_hh[hj], bhz_e = b_hh[NH+hj], bhn_e = b_hh[2*NH+hj];
    const float bir_c = bc_ih[hj], biz_c = bc_ih[NH+hj], bin_c = bc_ih[2*NH+hj];
    const float bhr_c = bc_hh[hj], bhz_c = bc_hh[NH+hj], bhn_c = bc_hh[2*NH+hj];
    const float be = b_e[hj];
    float we[NKIN];
    #pragma unroll
    for (int k = 0; k < NKIN; ++k) we[k] = W_e[hj*NKIN + k];

    float yreg[4];
    #pragma unroll
    for (int i = 0; i < 4; ++i) { yreg[i] = 0.0f; sh_y[bbase+i][hj] = 0.0f; }
    __syncthreads();

    // ---------------- encoder GRU (64 steps) ----------------
    {
        float wih[3][12];
        #pragma unroll
        for (int g = 0; g < 3; ++g)
            #pragma unroll
            for (int k = 0; k < 12; ++k) wih[g][k] = W_ih[(g*NH + hj)*12 + k];

        for (int t = 0; t < NTP; ++t) {
            if (tid < BT*12) {
                int b = tid / 12, k = tid - b*12;
                float v = (k < NKIN) ? pre_x[((size_t)t*NB + b0 + b)*NKIN + k]
                                     : pre_y[((size_t)t*NB + b0 + b)*NKOUT + (k - NKIN)];
                sh_in[b][k] = v;
            }
            __syncthreads();
            float gi[3][4] = {{0,0,0,0},{0,0,0,0},{0,0,0,0}};
            #pragma unroll
            for (int k = 0; k < 12; ++k) {
                #pragma unroll
                for (int i = 0; i < 4; ++i) {
                    float xv = sh_in[bbase+i][k];
                    gi[0][i] += wih[0][k]*xv; gi[1][i] += wih[1][k]*xv; gi[2][i] += wih[2][k]*xv;
                }
            }
            float gh[3][4] = {{0,0,0,0},{0,0,0,0},{0,0,0,0}};
            gemv3_128(W_hh, sh_y, hj, bbase, gh);
            float hn[4];
            #pragma unroll
            for (int i = 0; i < 4; ++i) {
                float r = fsig (gi[0][i] + bir_e + gh[0][i] + bhr_e);
                float z = fsig (gi[1][i] + biz_e + gh[1][i] + bhz_e);
                float n = ftanh(gi[2][i] + bin_e + r*(gh[2][i] + bhn_e));
                hn[i] = (1.0f - z)*n + z*yreg[i];
            }
            __syncthreads();
            #pragma unroll
            for (int i = 0; i < 4; ++i) { yreg[i] = hn[i]; sh_y[bbase+i][hj] = hn[i]; }
            __syncthreads();
        }
    }

    // ---------------- RK4 over 128 intervals ----------------
    float giA[3][4];   // gi of x at interval start (carried: x1 -> next x0)
    float gim[3][4];

    for (int st = 0; st < NL; ++st) {
        // control points u0, um, u1 for this interval
        if (tid < BT*NKIN) {
            int b = tid >> 3, k = tid & 7;
            size_t col = (size_t)(b0 + b)*NKIN + k;
            float y0v = (st == 0) ? pre_x[(size_t)(NTP-1)*BKIN + col]
                                  : fx[(size_t)(st-1)*BKIN + col];
            float y1v = fx[(size_t)st*BKIN + col];
            float mi  = M[(size_t)st*BKIN + col];
            float mi1 = M[(size_t)(st+1)*BKIN + col];
            sh_u[0][b][k] = y0v;
            sh_u[2][b][k] = y1v;
            sh_u[1][b][k] = 0.5f*(y0v + y1v) - (0.01f/16.0f)*(mi + mi1);
        }
        __syncthreads();

        // x = tanh(W_e u + b_e) for midpoint and endpoint (+ start on step 0)
        #pragma unroll
        for (int i = 0; i < 4; ++i) {
            float am = be, a1 = be;
            #pragma unroll
            for (int k = 0; k < NKIN; ++k) {
                am += we[k]*sh_u[1][bbase+i][k];
                a1 += we[k]*sh_u[2][bbase+i][k];
            }
            sh_xm[bbase+i][hj] = ftanh(am);
            sh_x1[bbase+i][hj] = ftanh(a1);
        }
        if (st == 0) {
            #pragma unroll
            for (int i = 0; i < 4; ++i) {
                float a0 = be;
                #pragma unroll
                for (int k = 0; k < NKIN; ++k) a0 += we[k]*sh_u[0][bbase+i][k];
                sh_x0[bbase+i][hj] = ftanh(a0);
            }
        }
        __syncthreads();

        if (st == 0) {
            #pragma unroll
            for (int g = 0; g < 3; ++g)
                #pragma unroll
                for (int i = 0; i < 4; ++i) giA[g][i] = 0.0f;
            gemv3_128(Wc_ih, sh_x0, hj, bbase, giA);
        }
        #pragma unroll
        for (int g = 0; g < 3; ++g)
            #pragma unroll
            for (int i = 0; i < 4; ++i) gim[g][i] = 0.0f;
        gemv3_128(Wc_ih, sh_xm, hj, bbase, gim);

        float Ksum[4], Kprev[4];
        // ---- k1 : gru(x0, y) - y ----  (note hs/UT = 1, so K = hs*k)
        {
            float gh[3][4] = {{0,0,0,0},{0,0,0,0},{0,0,0,0}};
            gemv3_128(Wc_hh, sh_y, hj, bbase, gh);
            #pragma unroll
            for (int i = 0; i < 4; ++i) {
                float r = fsig (giA[0][i] + bir_c + gh[0][i] + bhr_c);
                float z = fsig (giA[1][i] + biz_c + gh[1][i] + bhz_c);
                float n = ftanh(giA[2][i] + bin_c + r*(gh[2][i] + bhn_c));
                float K = (1.0f - z)*n + z*yreg[i] - yreg[i];
                Ksum[i] = K; Kprev[i] = K;
                sh_ye[bbase+i][hj] = yreg[i] + 0.5f*K;
            }
            __syncthreads();
        }
        // ---- k2 ----
        {
            float gh[3][4] = {{0,0,0,0},{0,0,0,0},{0,0,0,0}};
            gemv3_128(Wc_hh, sh_ye, hj, bbase, gh);
            #pragma unroll
            for (int i = 0; i < 4; ++i) {
                float yin = yreg[i] + 0.5f*Kprev[i];
                float r = fsig (gim[0][i] + bir_c + gh[0][i] + bhr_c);
                float z = fsig (gim[1][i] + biz_c + gh[1][i] + bhz_c);
                float n = ftanh(gim[2][i] + bin_c + r*(gh[2][i] + bhn_c));
                float K = (1.0f - z)*n + z*yin - yin;
                Ksum[i] += 2.0f*K; Kprev[i] = K;
            }
            __syncthreads();
            #pragma unroll
            for (int i = 0; i < 4; ++i) sh_ye[bbase+i][hj] = yreg[i] + 0.5f*Kprev[i];
            __syncthreads();
        }
        // ---- k3 ----
        {
            float gh[3][4] = {{0,0,0,0},{0,0,0,0},{0,0,0,0}};
            gemv3_128(Wc_hh, sh_ye, hj, bbase, gh);
            #pragma unroll
            for (int i = 0; i < 4; ++i) {
                float yin = yreg[i] + 0.5f*Kprev[i];
                float r = fsig (gim[0][i] + bir_c + gh[0][i] + bhr_c);
                float z = fsig (gim[1][i] + biz_c + gh[1][i] + bhz_c);
                float n = ftanh(gim[2][i] + bin_c + r*(gh[2][i] + bhn_c));
                float K = (1.0f - z)*n + z*yin - yin;
                Ksum[i] += 2.0f*K; Kprev[i] = K;
            }
            __syncthreads();
            #pragma unroll
            for (int i = 0; i < 4; ++i) sh_ye[bbase+i][hj] = yreg[i] + Kprev[i];
            __syncthreads();
        }
        // ---- k4 + y update ----
        {
            #pragma unroll
            for (int g = 0; g < 3; ++g)
                #pragma unroll
                for (int i = 0; i < 4; ++i) giA[g][i] = 0.0f;
            gemv3_128(Wc_ih, sh_x1, hj, bbase, giA);   // becomes gi0 of next step
            float gh[3][4] = {{0,0,0,0},{0,0,0,0},{0,0,0,0}};
            gemv3_128(Wc_hh, sh_ye, hj, bbase, gh);
            #pragma unroll
            for (int i = 0; i < 4; ++i) {
                float yin = yreg[i] + Kprev[i];
                float r = fsig (giA[0][i] + bir_c + gh[0][i] + bhr_c);
                float z = fsig (giA[1][i] + biz_c + gh[1][i] + bhz_c);
                float n = ftanh(giA[2][i] + bin_c + r*(gh[2][i] + bhn_c));
                float K = (1.0f - z)*n + z*yin - yin;
                Ksum[i] += K;
                yreg[i] += (1.0f/6.0f)*Ksum[i];
            }
            __syncthreads();
            #pragma unroll
            for (int i = 0; i < 4; ++i) sh_y[bbase+i][hj] = yreg[i];
            __syncthreads();
        }
        // ---- head: o = tanh(y @ W1^T); out = o @ W2^T ----
        {
            float ha[2][4] = {{0,0,0,0},{0,0,0,0}};
            const float4* __restrict__ w1a = (const float4*)W1 + hj*32;
            const float4* __restrict__ w1b = (const float4*)W1 + (NH + hj)*32;
            #pragma unroll 4
            for (int k4 = 0; k4 < 32; ++k4) {
                float4 p = w1a[k4], q = w1b[k4];
                #pragma unroll
                for (int i = 0; i < 4; ++i) {
                    float4 y = *(const float4*)&sh_y[bbase+i][k4*4];
                    ha[0][i] += p.x*y.x + p.y*y.y + p.z*y.z + p.w*y.w;
                    ha[1][i] += q.x*y.x + q.y*y.y + q.z*y.z + q.w*y.w;
                }
            }
            #pragma unroll
            for (int i = 0; i < 4; ++i) {
                sh_o[bbase+i][hj]      = ftanh(ha[0][i]);
                sh_o[bbase+i][NH + hj] = ftanh(ha[1][i]);
            }
            __syncthreads();
            if (tid < BT*NKOUT) {
                int b = tid >> 2, ko = tid & 3;
                const float4* __restrict__ w2 = (const float4*)(W2 + ko*2*NH);
                float s = 0.0f;
                #pragma unroll 8
                for (int k4 = 0; k4 < 64; ++k4) {
                    float4 w  = w2[k4];
                    float4 ov = *(const float4*)&sh_o[b][k4*4];
                    s += w.x*ov.x + w.y*ov.y + w.z*ov.z + w.w*ov.w;
                }
                out[((size_t)st*NB + b0 + b)*NKOUT + ko] = s;
            }
            // next iteration's first __syncthreads orders sh_o reuse
        }
    }
}

extern "C" void kernel_launch(void* const* d_in, const int* in_sizes, int n_in,
                              void* d_out, int out_size, void* d_ws, size_t ws_size,
                              hipStream_t stream)
{
    const float* pre_x = (const float*)d_in[0];
    const float* pre_y = (const float*)d_in[1];
    const float* fx    = (const float*)d_in[2];
    const float* W_ih  = (const float*)d_in[3];
    const float* W_hh  = (const float*)d_in[4];
    const float* b_ih  = (const float*)d_in[5];
    const float* b_hh  = (const float*)d_in[6];
    const float* W_e   = (const float*)d_in[7];
    const float* b_e   = (const float*)d_in[8];
    const float* Wc_ih = (const float*)d_in[9];
    const float* Wc_hh = (const float*)d_in[10];
    const float* bc_ih = (const float*)d_in[11];
    const float* bc_hh = (const float*)d_in[12];
    const float* W1    = (const float*)d_in[13];
    const float* W2    = (const float*)d_in[14];
    float* out = (float*)d_out;
    float* M   = (float*)d_ws;   // (L+1)*B*KIN floats = 16.9 MB of scratch

    spline_kernel<<<dim3((NB*NKIN)/256), dim3(256), 0, stream>>>(pre_x, fx, M);
    fused_kernel<<<dim3(NB/BT), dim3(NTHR), 0, stream>>>(
        pre_x, pre_y, fx, W_ih, W_hh, b_ih, b_hh, W_e, b_e,
        Wc_ih, Wc_hh, bc_ih, bc_hh, W1, W2, M, out);
}

// Round 2
// 790.893 us; speedup vs baseline: 26.2287x; 26.2287x over previous
//
#include <hip/hip_runtime.h>
#include <math.h>

#define NB    4096
#define NH    128
#define NKIN  8
#define NKOUT 4
#define NTP   64
#define NL    128
#define BKIN  (NB*NKIN)

typedef __attribute__((ext_vector_type(8))) short short8;
typedef __attribute__((ext_vector_type(4))) float f32x4;

__device__ __forceinline__ short f2bf(float f) {
    union { float f; unsigned u; } v; v.f = f;
    unsigned u = v.u;
    unsigned r = (u + 0x7fffu + ((u >> 16) & 1u)) >> 16;
    return (short)r;
}
__device__ __forceinline__ float sigf(float x)   { return __builtin_amdgcn_rcpf(1.0f + __expf(-x)); }
__device__ __forceinline__ float tanhf_(float x) { return 1.0f - 2.0f*__builtin_amdgcn_rcpf(1.0f + __expf(2.0f*x)); }

// ---------------- spline: Thomas solve -> UM (midpoint control values), in place ----
__global__ void spline_um_kernel(const float* __restrict__ pre_x,
                                 const float* __restrict__ fx,
                                 float* __restrict__ UM)
{
    __shared__ float cp[128];
    if (threadIdx.x == 0) {
        float c = 0.f;
        for (int j = 1; j <= 127; ++j) { c = 1.0f/(4.0f - c); cp[j] = c; }
    }
    __syncthreads();
    int col = blockIdx.x*256 + threadIdx.x;
    const float r6 = 6.0f/(0.1f*0.1f);
    const float KK = 0.01f/16.0f;   // hs^2/16
    // forward elimination: d'_j stored in UM[j]
    float y0 = pre_x[(size_t)(NTP-1)*BKIN + col];   // ys[0]
    float y1 = fx[col];                              // ys[1]
    float d = 0.f;
    for (int j = 1; j <= 127; ++j) {
        float y2 = fx[(size_t)j*BKIN + col];         // ys[j+1]
        float r  = r6*(y0 - 2.f*y1 + y2);
        d = (r - d)*cp[j];
        UM[(size_t)j*BKIN + col] = d;
        y0 = y1; y1 = y2;
    }
    // backward substitution, emit UM[j] = 0.5*(ys[j]+ys[j+1]) - KK*(M_j+M_{j+1})
    float xn  = 0.f;                                  // M_{j+1}
    float yj1 = fx[(size_t)127*BKIN + col];           // ys[128]
    for (int j = 127; j >= 1; --j) {
        float dj = UM[(size_t)j*BKIN + col];
        float x  = dj - cp[j]*xn;                     // M_j
        float yj = fx[(size_t)(j-1)*BKIN + col];      // ys[j]
        UM[(size_t)j*BKIN + col] = 0.5f*(yj + yj1) - KK*(x + xn);
        xn = x; yj1 = yj;
    }
    float ys0 = pre_x[(size_t)(NTP-1)*BKIN + col];
    UM[col] = 0.5f*(ys0 + yj1) - KK*xn;               // M_0 = 0, M_1 = xn
}

// ---------------- prep: swizzle W1/W2 into MFMA fragment order (bf16) ----------------
__global__ void prep_frags(const float* __restrict__ W1, const float* __restrict__ W2,
                           short* __restrict__ w1f, short* __restrict__ w2f)
{
    int tid = threadIdx.x;
    // W1 as B-operand: B[k][n] = W1[n][k]; frag ((t*4+c)*64+lane)*8+j, t<16,c<4
    for (int idx = tid; idx < 16*4*64*8; idx += 256) {
        int j = idx & 7, lane = (idx >> 3) & 63, fc = idx >> 9;
        int t = fc >> 2, c = fc & 3;
        int n = t*16 + (lane & 15);
        int k = c*32 + (lane >> 4)*8 + j;
        w1f[idx] = f2bf(W1[n*NH + k]);
    }
    // W2 as A-operand (rows ko padded to 16): A[m][k], frag (c*64+lane)*8+j, c<8
    for (int idx = tid; idx < 8*64*8; idx += 256) {
        int j = idx & 7, lane = (idx >> 3) & 63, c = idx >> 9;
        int m = lane & 15;
        int k = c*32 + (lane >> 4)*8 + j;
        w2f[idx] = (m < NKOUT) ? f2bf(W2[m*2*NH + k]) : (short)0;
    }
}

// ---------------- fused encoder + RK4 + head (MFMA) ----------------
__device__ __forceinline__ void gemm12(const short* base, const short8 (&B)[3][4], f32x4 (&c)[3])
{
    #pragma unroll
    for (int kc = 0; kc < 4; ++kc) {
        short8 a = *(const short8*)(base + kc*32);
        #pragma unroll
        for (int g = 0; g < 3; ++g)
            c[g] = __builtin_amdgcn_mfma_f32_16x16x32_bf16(a, B[g][kc], c[g], 0, 0, 0);
    }
}

__device__ __forceinline__ void writeA(short* buf, int stride, int col, int quad, f32x4 v)
{
    #pragma unroll
    for (int r = 0; r < 4; ++r) buf[(quad*4 + r)*stride + col] = f2bf(v[r]);
}

__device__ __forceinline__ void gateK(const f32x4 (&gi)[3], const f32x4 (&gh)[3],
                                      const f32x4& yin, float brz, float bzz,
                                      float bin_, float bhn_, f32x4& K)
{
    #pragma unroll
    for (int r = 0; r < 4; ++r) {
        float rg = sigf(gi[0][r] + gh[0][r] + brz);
        float zg = sigf(gi[1][r] + gh[1][r] + bzz);
        float ng = tanhf_(gi[2][r] + bin_ + rg*(gh[2][r] + bhn_));
        K[r] = (1.0f - zg)*(ng - yin[r]);
    }
}

__global__ void __launch_bounds__(512, 2)
fused_kernel(const float* __restrict__ pre_x, const float* __restrict__ pre_y,
             const float* __restrict__ fx,
             const float* __restrict__ W_ih, const float* __restrict__ W_hh,
             const float* __restrict__ b_ih, const float* __restrict__ b_hh,
             const float* __restrict__ W_e,  const float* __restrict__ b_e,
             const float* __restrict__ Wc_ih,const float* __restrict__ Wc_hh,
             const float* __restrict__ bc_ih,const float* __restrict__ bc_hh,
             const float* __restrict__ UM,   const short* __restrict__ w1f,
             const short* __restrict__ w2f,  float* __restrict__ out)
{
    __shared__ __align__(16) short Yb [16*136];
    __shared__ __align__(16) short E0 [16*136];
    __shared__ __align__(16) short E1 [16*136];
    __shared__ __align__(16) short XMb[16*136];
    __shared__ __align__(16) short X1b[16*136];
    __shared__ __align__(16) short UMb[16*40];
    __shared__ __align__(16) short U1b[16*40];
    __shared__ __align__(16) short OB [16*264];

    const int tid  = threadIdx.x;
    const int w    = tid >> 6;
    const int lane = tid & 63;
    const int quad = lane >> 4;
    const int m    = lane & 15;
    const int hcol = w*16 + m;            // this wave's h/y column
    const int b0   = blockIdx.x * 16;
    const f32x4 z4 = {0.f, 0.f, 0.f, 0.f};

    // zero LDS that needs zeros (h0 = 0; zero-padded K for expand/encoder inputs)
    for (int i = tid; i < 2176; i += 512) Yb[i] = 0;
    for (int i = tid; i < 640;  i += 512) { UMb[i] = 0; U1b[i] = 0; }

    // ---- B-fragment preloads (one-time, raw fp32 -> bf16 RNE) ----
    short8 Bhh[3][4], Bih_c[3][4];
    #pragma unroll
    for (int g = 0; g < 3; ++g)
        #pragma unroll
        for (int c = 0; c < 4; ++c) {
            int n = g*NH + hcol, kb = c*32 + quad*8;
            short8 f1, f2;
            #pragma unroll
            for (int j = 0; j < 8; ++j) {
                f1[j] = f2bf(Wc_hh[n*NH + kb + j]);
                f2[j] = f2bf(Wc_ih[n*NH + kb + j]);
            }
            Bhh[g][c] = f1; Bih_c[g][c] = f2;
        }
    short8 Ehh[3][4];
    #pragma unroll
    for (int g = 0; g < 3; ++g)
        #pragma unroll
        for (int c = 0; c < 4; ++c) {
            int n = g*NH + hcol, kb = c*32 + quad*8;
            short8 f1;
            #pragma unroll
            for (int j = 0; j < 8; ++j) f1[j] = f2bf(W_hh[n*NH + kb + j]);
            Ehh[g][c] = f1;
        }
    short8 Eih[3];
    #pragma unroll
    for (int g = 0; g < 3; ++g) {
        short8 f1;
        #pragma unroll
        for (int j = 0; j < 8; ++j) {
            int k = quad*8 + j;
            f1[j] = (k < 12) ? f2bf(W_ih[(g*NH + hcol)*12 + k]) : (short)0;
        }
        Eih[g] = f1;
    }
    short8 Bexp;
    #pragma unroll
    for (int j = 0; j < 8; ++j) {
        int k = quad*8 + j;
        Bexp[j] = (k < NKIN) ? f2bf(W_e[hcol*NKIN + k]) : (short)0;
    }
    const float be   = b_e[hcol];
    const float brz  = bc_ih[hcol]        + bc_hh[hcol];
    const float bzz  = bc_ih[NH + hcol]   + bc_hh[NH + hcol];
    const float bin_ = bc_ih[2*NH + hcol];
    const float bhn_ = bc_hh[2*NH + hcol];
    const float erz  = b_ih[hcol]         + b_hh[hcol];
    const float ezz  = b_ih[NH + hcol]    + b_hh[NH + hcol];
    const float ein_ = b_ih[2*NH + hcol];
    const float ehn_ = b_hh[2*NH + hcol];

    f32x4 y = z4;   // encoder h, then ODE state

    // ================= encoder GRU (64 steps) =================
    const int eb = tid / 12, ek = tid - eb*12;   // staging map (tid<192)
    float encv = 0.f;
    if (tid < 192)
        encv = (ek < NKIN) ? pre_x[((size_t)0*NB + b0 + eb)*NKIN + ek]
                           : pre_y[((size_t)0*NB + b0 + eb)*NKOUT + (ek - NKIN)];
    __syncthreads();   // LDS zeros visible
    for (int t = 0; t < NTP; ++t) {
        if (tid < 192) {
            UMb[eb*40 + ek] = f2bf(encv);
            if (t + 1 < NTP)
                encv = (ek < NKIN) ? pre_x[((size_t)(t+1)*NB + b0 + eb)*NKIN + ek]
                                   : pre_y[((size_t)(t+1)*NB + b0 + eb)*NKOUT + (ek - NKIN)];
        }
        __syncthreads();
        f32x4 gi[3] = {z4, z4, z4};
        {
            short8 a = *(const short8*)(UMb + m*40 + quad*8);
            #pragma unroll
            for (int g = 0; g < 3; ++g)
                gi[g] = __builtin_amdgcn_mfma_f32_16x16x32_bf16(a, Eih[g], gi[g], 0, 0, 0);
        }
        f32x4 gh[3] = {z4, z4, z4};
        gemm12(Yb + m*136 + quad*8, Ehh, gh);
        f32x4 K;
        gateK(gi, gh, y, erz, ezz, ein_, ehn_, K);
        #pragma unroll
        for (int r = 0; r < 4; ++r) y[r] += K[r];
        __syncthreads();
        writeA(Yb, 136, hcol, quad, y);
    }
    // re-zero enc-only columns 8..11 of UMb for RK4 staging (cols 12..39 still zero)
    if (tid < 64) UMb[(tid >> 2)*40 + 8 + (tid & 3)] = 0;

    // ================= initial gi0 from u0 = pre_x[-1] =================
    const int sb = tid >> 3, sk = tid & 7;            // staging map (tid<128)
    const size_t scol = (size_t)(b0 + sb)*NKIN + sk;
    if (tid < 128) UMb[sb*40 + sk] = f2bf(pre_x[(size_t)(NTP-1)*BKIN + scol]);
    __syncthreads();
    f32x4 gi0[3] = {z4, z4, z4};
    {
        short8 a = *(const short8*)(UMb + m*40 + quad*8);
        f32x4 c0 = z4;
        c0 = __builtin_amdgcn_mfma_f32_16x16x32_bf16(a, Bexp, c0, 0, 0, 0);
        f32x4 xv;
        #pragma unroll
        for (int r = 0; r < 4; ++r) xv[r] = tanhf_(c0[r] + be);
        writeA(XMb, 136, hcol, quad, xv);
    }
    __syncthreads();
    gemm12(XMb + m*136 + quad*8, Bih_c, gi0);

    // staging prefetch for st=0
    float fxv = 0.f, umv = 0.f;
    if (tid < 128) { fxv = fx[scol]; umv = UM[scol]; }

    const short8* W1F = (const short8*)w1f;
    const short8* W2F = (const short8*)w2f;

    // ================= RK4 over 128 intervals =================
    for (int st = 0; st < NL; ++st) {
        if (tid < 128) {
            U1b[sb*40 + sk] = f2bf(fxv);
            UMb[sb*40 + sk] = f2bf(umv);
        }
        __syncthreads();                                        // (1)
        // expand: x_mid, x_end
        f32x4 xmv, x1v;
        {
            short8 am = *(const short8*)(UMb + m*40 + quad*8);
            short8 a1 = *(const short8*)(U1b + m*40 + quad*8);
            f32x4 cm = z4, c1 = z4;
            cm = __builtin_amdgcn_mfma_f32_16x16x32_bf16(am, Bexp, cm, 0, 0, 0);
            c1 = __builtin_amdgcn_mfma_f32_16x16x32_bf16(a1, Bexp, c1, 0, 0, 0);
            #pragma unroll
            for (int r = 0; r < 4; ++r) {
                xmv[r] = tanhf_(cm[r] + be);
                x1v[r] = tanhf_(c1[r] + be);
            }
        }
        writeA(XMb, 136, hcol, quad, xmv);
        writeA(X1b, 136, hcol, quad, x1v);
        if (tid < 128 && st + 1 < NL) {                         // prefetch next staging
            fxv = fx[(size_t)(st+1)*BKIN + scol];
            umv = UM[(size_t)(st+1)*BKIN + scol];
        }
        __syncthreads();                                        // (2)
        f32x4 gim[3] = {z4, z4, z4}, gi1[3] = {z4, z4, z4};
        gemm12(XMb + m*136 + quad*8, Bih_c, gim);
        gemm12(X1b + m*136 + quad*8, Bih_c, gi1);
        // ---- k1 ----
        f32x4 gh[3] = {z4, z4, z4};
        gemm12(Yb + m*136 + quad*8, Bhh, gh);
        f32x4 K1, Ks, ye;
        gateK(gi0, gh, y, brz, bzz, bin_, bhn_, K1);
        #pragma unroll
        for (int r = 0; r < 4; ++r) { Ks[r] = K1[r]; ye[r] = y[r] + 0.5f*K1[r]; }
        writeA(E0, 136, hcol, quad, ye);
        __syncthreads();                                        // (3)
        // ---- k2 ----
        gh[0] = z4; gh[1] = z4; gh[2] = z4;
        gemm12(E0 + m*136 + quad*8, Bhh, gh);
        f32x4 K2;
        gateK(gim, gh, ye, brz, bzz, bin_, bhn_, K2);
        #pragma unroll
        for (int r = 0; r < 4; ++r) { Ks[r] += 2.f*K2[r]; ye[r] = y[r] + 0.5f*K2[r]; }
        writeA(E1, 136, hcol, quad, ye);
        __syncthreads();                                        // (4)
        // ---- k3 ----
        gh[0] = z4; gh[1] = z4; gh[2] = z4;
        gemm12(E1 + m*136 + quad*8, Bhh, gh);
        f32x4 K3;
        gateK(gim, gh, ye, brz, bzz, bin_, bhn_, K3);
        #pragma unroll
        for (int r = 0; r < 4; ++r) { Ks[r] += 2.f*K3[r]; ye[r] = y[r] + K3[r]; }
        writeA(E0, 136, hcol, quad, ye);
        __syncthreads();                                        // (5)
        // ---- k4 + y update ----
        gh[0] = z4; gh[1] = z4; gh[2] = z4;
        gemm12(E0 + m*136 + quad*8, Bhh, gh);
        f32x4 K4;
        gateK(gi1, gh, ye, brz, bzz, bin_, bhn_, K4);
        #pragma unroll
        for (int r = 0; r < 4; ++r) y[r] += (1.0f/6.0f)*(Ks[r] + K4[r]);
        gi0[0] = gi1[0]; gi0[1] = gi1[1]; gi0[2] = gi1[2];
        writeA(Yb, 136, hcol, quad, y);
        __syncthreads();                                        // (6)
        // ---- head stage 1: o = tanh(y @ W1^T), 2 N-tiles per wave ----
        {
            f32x4 o0 = z4, o1 = z4;
            #pragma unroll
            for (int kc = 0; kc < 4; ++kc) {
                short8 a  = *(const short8*)(Yb + m*136 + quad*8 + kc*32);
                short8 bA = W1F[((w    )*4 + kc)*64 + lane];
                short8 bB = W1F[((w + 8)*4 + kc)*64 + lane];
                o0 = __builtin_amdgcn_mfma_f32_16x16x32_bf16(a, bA, o0, 0, 0, 0);
                o1 = __builtin_amdgcn_mfma_f32_16x16x32_bf16(a, bB, o1, 0, 0, 0);
            }
            #pragma unroll
            for (int r = 0; r < 4; ++r) {
                OB[(quad*4 + r)*264 + hcol]       = f2bf(tanhf_(o0[r]));
                OB[(quad*4 + r)*264 + 128 + hcol] = f2bf(tanhf_(o1[r]));
            }
        }
        __syncthreads();                                        // (7)
        // ---- head stage 2 (wave 0): out^T[ko][b] = W2 @ o^T ----
        if (w == 0) {
            f32x4 oc = z4;
            #pragma unroll
            for (int c = 0; c < 8; ++c) {
                short8 bo = *(const short8*)(OB + m*264 + c*32 + quad*8);
                short8 aw = W2F[c*64 + lane];
                oc = __builtin_amdgcn_mfma_f32_16x16x32_bf16(aw, bo, oc, 0, 0, 0);
            }
            if (quad == 0)
                *(f32x4*)(out + ((size_t)st*NB + b0 + m)*NKOUT) = oc;
        }
    }
}

extern "C" void kernel_launch(void* const* d_in, const int* in_sizes, int n_in,
                              void* d_out, int out_size, void* d_ws, size_t ws_size,
                              hipStream_t stream)
{
    const float* pre_x = (const float*)d_in[0];
    const float* pre_y = (const float*)d_in[1];
    const float* fx    = (const float*)d_in[2];
    const float* W_ih  = (const float*)d_in[3];
    const float* W_hh  = (const float*)d_in[4];
    const float* b_ih  = (const float*)d_in[5];
    const float* b_hh  = (const float*)d_in[6];
    const float* W_e   = (const float*)d_in[7];
    const float* b_e   = (const float*)d_in[8];
    const float* Wc_ih = (const float*)d_in[9];
    const float* Wc_hh = (const float*)d_in[10];
    const float* bc_ih = (const float*)d_in[11];
    const float* bc_hh = (const float*)d_in[12];
    const float* W1    = (const float*)d_in[13];
    const float* W2    = (const float*)d_in[14];
    float* out = (float*)d_out;

    float* UM  = (float*)d_ws;                                        // 128*4096*8 fp32 = 16.78 MB
    short* w1f = (short*)((char*)d_ws + (size_t)NL*NB*NKIN*4);        // 32768 shorts
    short* w2f = w1f + 16*4*64*8;                                     // 4096 shorts

    prep_frags<<<dim3(1), dim3(256), 0, stream>>>(W1, W2, w1f, w2f);
    spline_um_kernel<<<dim3((NB*NKIN)/256), dim3(256), 0, stream>>>(pre_x, fx, UM);
    fused_kernel<<<dim3(NB/16), dim3(512), 0, stream>>>(
        pre_x, pre_y, fx, W_ih, W_hh, b_ih, b_hh, W_e, b_e,
        Wc_ih, Wc_hh, bc_ih, bc_hh, UM, w1f, w2f, out);
}